// Round 7
// baseline (37.562 us; speedup 1.0000x reference)
//
#include <hip/hip_runtime.h>

// Causal linear attention (ELU+1), B=2 S=2048 H=16 D=64, chunk C=128.
// K1 prep_state: stage k,v -> bf16 swizzled exports + per-chunk state (bf16) via MFMA.
// K3 lin_attn_out: prologue prefix-sums chunk states (L2-resident) -> S0L/kzl;
//                  swapped-operand QK^T (S^T in regs) + bpermute repack -> PV MFMA.

#define BB 2
#define SS 2048
#define HH 16
#define DD 64
#define CC 128
#define NC (SS / CC)           // 16
#define BH (BB * HH)           // 32
#define NCHUNK (BH * NC)       // 512

#define ST_STRIDE 8448LL       // bytes: 4096 bf16 state + 64 fp32 kz
#define WS_KB (512LL * ST_STRIDE)           // kbg
#define WS_VT (WS_KB + 512LL * 16384)       // vtg

typedef __attribute__((ext_vector_type(8))) short bf16x8;
typedef __attribute__((ext_vector_type(4))) float f32x4;

__device__ __forceinline__ float phi(float x) {
    return x > 0.f ? x + 1.f : __expf(x);
}
__device__ __forceinline__ unsigned short f2bf(float x) {
    unsigned int u = __float_as_uint(x);
    u += 0x7fffu + ((u >> 16) & 1u);
    return (unsigned short)(u >> 16);
}
__device__ __forceinline__ float bf2f(unsigned short b) {
    return __uint_as_float(((unsigned int)b) << 16);
}
__device__ __forceinline__ void gload16(const void* g, void* lds) {
    __builtin_amdgcn_global_load_lds(
        (const __attribute__((address_space(1))) unsigned int*)g,
        (__attribute__((address_space(3))) unsigned int*)lds, 16, 0, 0);
}

// ---------------- Kernel 1: prep + per-chunk state ----------------
__global__ __launch_bounds__(256, 2)
void prep_state(const float* __restrict__ qk, const float* __restrict__ v,
                char* __restrict__ st, unsigned short* __restrict__ kbg,
                unsigned short* __restrict__ vtg) {
    __shared__ unsigned short Kt[DD][136];   // [d][s] phi(k)
    __shared__ unsigned short Vt[DD][136];   // [e][s] v

    const int tid = threadIdx.x, blk = blockIdx.x;
    const int bh = blk / NC, c = blk % NC, b = bh / HH, h = bh % HH;
    const int s0 = c * CC;
    const int lr = tid >> 4, lc = (tid & 15) * 4;
    char* kbc = (char*)kbg + (size_t)blk * 16384;

    #pragma unroll
    for (int it = 0; it < 8; ++it) {
        int row = it * 16 + lr;
        size_t ka = ((size_t)((b * SS + s0 + row) * 2 + 1)) * (HH * DD) + h * DD + lc;
        float4 kv = *(const float4*)(qk + ka);
        ushort4 kq = make_ushort4(f2bf(phi(kv.x)), f2bf(phi(kv.y)),
                                  f2bf(phi(kv.z)), f2bf(phi(kv.w)));
        *(ushort4*)(kbc + row * 128 + ((lc * 2) ^ ((row & 7) << 4))) = kq;
        Kt[lc + 0][row] = kq.x; Kt[lc + 1][row] = kq.y;
        Kt[lc + 2][row] = kq.z; Kt[lc + 3][row] = kq.w;
        size_t va = ((size_t)((b * SS + s0 + row) * HH + h)) * DD + lc;
        float4 vv = *(const float4*)(v + va);
        Vt[lc + 0][row] = f2bf(vv.x); Vt[lc + 1][row] = f2bf(vv.y);
        Vt[lc + 2][row] = f2bf(vv.z); Vt[lc + 3][row] = f2bf(vv.w);
    }
    __syncthreads();

    // export V^T (swizzled 256B rows)
    {
        char* vtc = (char*)vtg + (size_t)blk * 16384;
        int e = tid >> 2, sq = (tid & 3) * 32;
        #pragma unroll
        for (int k8 = 0; k8 < 4; ++k8) {
            int s = sq + k8 * 8;
            bf16x8 val = *(const bf16x8*)&Vt[e][s];
            *(bf16x8*)(vtc + e * 256 + ((s * 2) ^ ((e & 7) << 4))) = val;
        }
    }

    // MFMA: state[e][d] = sum_s V[s][e] K[s][d]; kz[d] via ones-A (wave 0)
    const int w = tid >> 6, lane = tid & 63, g = lane >> 4, ln = lane & 15;
    {
        bf16x8 av[4];
        #pragma unroll
        for (int ks = 0; ks < 4; ++ks)
            av[ks] = *(const bf16x8*)&Vt[w * 16 + ln][ks * 32 + g * 8];
        bf16x8 ones;
        #pragma unroll
        for (int j = 0; j < 8; ++j) ones[j] = (short)0x3F80;

        char* stc = st + (size_t)blk * ST_STRIDE;
        #pragma unroll
        for (int n = 0; n < 4; ++n) {
            f32x4 a = {0.f, 0.f, 0.f, 0.f}, kz4 = {0.f, 0.f, 0.f, 0.f};
            #pragma unroll
            for (int ks = 0; ks < 4; ++ks) {
                bf16x8 bk = *(const bf16x8*)&Kt[n * 16 + ln][ks * 32 + g * 8];
                a = __builtin_amdgcn_mfma_f32_16x16x32_bf16(av[ks], bk, a, 0, 0, 0);
                if (w == 0)
                    kz4 = __builtin_amdgcn_mfma_f32_16x16x32_bf16(ones, bk, kz4, 0, 0, 0);
            }
            #pragma unroll
            for (int r = 0; r < 4; ++r)
                *(unsigned short*)(stc + (((w * 16 + g * 4 + r) * 64) + n * 16 + ln) * 2)
                    = f2bf(a[r]);
            if (w == 0 && g == 0)
                *(float*)(stc + 8192 + (n * 16 + ln) * 4) = kz4[0];
        }
    }
}

// ---------------- Kernel 3: prefix prologue + output via MFMA ----------------
__global__ __launch_bounds__(256, 2)
void lin_attn_out(const float* __restrict__ qk,
                  const unsigned short* __restrict__ kbg,
                  const unsigned short* __restrict__ vtg,
                  const char* __restrict__ st,
                  float* __restrict__ out) {
    __shared__ __align__(16) char KbL[16384];            // [s][d] swizzled
    __shared__ __align__(16) char VtL[16384];            // [e][s] swizzled
    __shared__ __align__(16) char S0L[8192];             // [e][d] swizzled
    __shared__ float kzl[DD];
    __shared__ float nul[4][32];

    const int tid = threadIdx.x, blk = blockIdx.x;
    const int bh = blk / NC, c = blk % NC, b = bh / HH, h = bh % HH;
    const int s0 = c * CC;
    const int w = tid >> 6, lane = tid & 63, g = lane >> 4, ln = lane & 15;
    const int wband = (blk & 1) ? (3 - w) : w;   // SIMD load balance across 2 blocks/CU

    // async stage K, V^T
    {
        const char* kbs = (const char*)kbg + (size_t)blk * 16384;
        const char* vts = (const char*)vtg + (size_t)blk * 16384;
        #pragma unroll
        for (int i = 0; i < 4; ++i) {
            gload16(kbs + w * 4096 + i * 1024 + lane * 16, KbL + w * 4096 + i * 1024);
            gload16(vts + w * 4096 + i * 1024 + lane * 16, VtL + w * 4096 + i * 1024);
        }
    }

    // prologue: prefix-sum of this bh's chunk states (< c) -> S0L swizzled + kzl
    {
        const char* stb = st + (size_t)(bh * NC) * ST_STRIDE;
        float acc[16];
        #pragma unroll
        for (int j = 0; j < 16; ++j) acc[j] = 0.f;
        for (int c2 = 0; c2 < c; ++c2) {
            const char* src = stb + (size_t)c2 * ST_STRIDE + tid * 32;
            bf16x8 x0 = *(const bf16x8*)src;
            bf16x8 x1 = *(const bf16x8*)(src + 16);
            #pragma unroll
            for (int j = 0; j < 8; ++j) {
                acc[j]     += bf2f((unsigned short)x0[j]);
                acc[j + 8] += bf2f((unsigned short)x1[j]);
            }
        }
        int e = tid >> 2, d0 = (tid & 3) * 16;   // elements
        bf16x8 o0, o1;
        #pragma unroll
        for (int j = 0; j < 8; ++j) {
            o0[j] = (short)f2bf(acc[j]);
            o1[j] = (short)f2bf(acc[j + 8]);
        }
        int sw = (e & 7) << 4;
        *(bf16x8*)(S0L + e * 128 + ((2 * d0) ^ sw)) = o0;
        *(bf16x8*)(S0L + e * 128 + ((2 * d0 + 16) ^ sw)) = o1;
        if (tid < DD) {
            float a = 0.f;
            for (int c2 = 0; c2 < c; ++c2)
                a += *(const float*)(stb + (size_t)c2 * ST_STRIDE + 8192 + 4 * tid);
            kzl[tid] = a;
        }
    }

    // q -> registers (phi + bf16)
    bf16x8 aq[2][2];
    #pragma unroll
    for (int m = 0; m < 2; ++m) {
        int tg = s0 + wband * 32 + m * 16 + ln;
        const float* qrow = qk + ((size_t)((b * SS + tg) * 2)) * (HH * DD) + h * DD;
        #pragma unroll
        for (int kb2 = 0; kb2 < 2; ++kb2) {
            float4 x0 = *(const float4*)(qrow + kb2 * 32 + g * 8);
            float4 x1 = *(const float4*)(qrow + kb2 * 32 + g * 8 + 4);
            bf16x8 f;
            f[0] = (short)f2bf(phi(x0.x)); f[1] = (short)f2bf(phi(x0.y));
            f[2] = (short)f2bf(phi(x0.z)); f[3] = (short)f2bf(phi(x0.w));
            f[4] = (short)f2bf(phi(x1.x)); f[5] = (short)f2bf(phi(x1.y));
            f[6] = (short)f2bf(phi(x1.z)); f[7] = (short)f2bf(phi(x1.w));
            aq[m][kb2] = f;
        }
    }
    __syncthreads();

    f32x4 O[2][4];
    #pragma unroll
    for (int m = 0; m < 2; ++m)
        #pragma unroll
        for (int n = 0; n < 4; ++n) O[m][n] = (f32x4){0.f, 0.f, 0.f, 0.f};

    // inter-chunk: O += Q * S0
    #pragma unroll
    for (int n = 0; n < 4; ++n) {
        int e = n * 16 + ln;
        bf16x8 b0 = *(const bf16x8*)(S0L + e * 128 + ((g * 16) ^ ((e & 7) << 4)));
        bf16x8 b1 = *(const bf16x8*)(S0L + e * 128 + ((64 + g * 16) ^ ((e & 7) << 4)));
        #pragma unroll
        for (int m = 0; m < 2; ++m) {
            O[m][n] = __builtin_amdgcn_mfma_f32_16x16x32_bf16(aq[m][0], b0, O[m][n], 0, 0, 0);
            O[m][n] = __builtin_amdgcn_mfma_f32_16x16x32_bf16(aq[m][1], b1, O[m][n], 0, 0, 0);
        }
    }

    // nu base: q . kz
    float nuA[2] = {0.f, 0.f};
    #pragma unroll
    for (int kb2 = 0; kb2 < 2; ++kb2)
        #pragma unroll
        for (int j = 0; j < 8; ++j) {
            float kzv = kzl[kb2 * 32 + g * 8 + j];
            nuA[0] = fmaf(bf2f((unsigned short)aq[0][kb2][j]), kzv, nuA[0]);
            nuA[1] = fmaf(bf2f((unsigned short)aq[1][kb2][j]), kzv, nuA[1]);
        }

    // causal s-block loop: swapped QK^T (S^T in regs) + bpermute repack -> PV
    const int srcA = ((lane & 16) << 1) + ln;   // source lane, j<4
    const bool hiT = (lane & 32) != 0;          // this lane's pa comes from tile ns=1
    for (int sblk = 0; sblk <= wband; ++sblk) {
        const bool diag = (sblk == wband);
        f32x4 ScT[2][2];   // [m][ns]: D[row=s_loc][col=t_loc]
        #pragma unroll
        for (int m = 0; m < 2; ++m)
            #pragma unroll
            for (int ns = 0; ns < 2; ++ns) ScT[m][ns] = (f32x4){0.f, 0.f, 0.f, 0.f};

        #pragma unroll
        for (int ns = 0; ns < 2; ++ns) {
            int s = sblk * 32 + ns * 16 + ln;
            const char* srow = KbL + s * 128;
            bf16x8 bk0 = *(const bf16x8*)(srow + ((g * 16) ^ ((s & 7) << 4)));
            bf16x8 bk1 = *(const bf16x8*)(srow + ((64 + g * 16) ^ ((s & 7) << 4)));
            #pragma unroll
            for (int m = 0; m < 2; ++m) {
                ScT[m][ns] = __builtin_amdgcn_mfma_f32_16x16x32_bf16(bk0, aq[m][0], ScT[m][ns], 0, 0, 0);
                ScT[m][ns] = __builtin_amdgcn_mfma_f32_16x16x32_bf16(bk1, aq[m][1], ScT[m][ns], 0, 0, 0);
            }
        }

        // diag mask (row=s_loc=ns*16+g*4+r, col=t_loc=m*16+ln) + nu partial
        #pragma unroll
        for (int m = 0; m < 2; ++m)
            #pragma unroll
            for (int ns = 0; ns < 2; ++ns)
                #pragma unroll
                for (int r = 0; r < 4; ++r) {
                    if (diag && (ns * 16 + g * 4 + r > m * 16 + ln))
                        ScT[m][ns][r] = 0.f;
                    nuA[m] += ScT[m][ns][r];
                }

        // V b-frags
        bf16x8 bv[4];
        #pragma unroll
        for (int n = 0; n < 4; ++n) {
            int e = n * 16 + ln;
            bv[n] = *(const bf16x8*)(VtL + e * 256 + ((sblk * 64 + g * 16) ^ ((e & 7) << 4)));
        }

        // repack S^T -> W A-frags via bpermute, then PV
        #pragma unroll
        for (int m = 0; m < 2; ++m) {
            bf16x8 pa;
            #pragma unroll
            for (int j = 0; j < 8; ++j) {
                int sl = (j < 4) ? srcA : (srcA + 16);
                float v0 = __shfl(ScT[m][0][j & 3], sl);
                float v1 = __shfl(ScT[m][1][j & 3], sl);
                pa[j] = (short)f2bf(hiT ? v1 : v0);
            }
            #pragma unroll
            for (int n = 0; n < 4; ++n)
                O[m][n] = __builtin_amdgcn_mfma_f32_16x16x32_bf16(pa, bv[n], O[m][n], 0, 0, 0);
        }
    }

    // nu reduce + normalize + store
    #pragma unroll
    for (int m = 0; m < 2; ++m) {
        float nt = nuA[m];
        nt += __shfl_xor(nt, 16);
        nt += __shfl_xor(nt, 32);
        if (g == 0) nul[w][m * 16 + ln] = nt;
    }
    asm volatile("s_waitcnt lgkmcnt(0)" ::: "memory");
    __builtin_amdgcn_sched_barrier(0);

    #pragma unroll
    for (int m = 0; m < 2; ++m) {
        float inv[4];
        #pragma unroll
        for (int r = 0; r < 4; ++r) inv[r] = 1.f / nul[w][m * 16 + g * 4 + r];
        #pragma unroll
        for (int n = 0; n < 4; ++n)
            #pragma unroll
            for (int r = 0; r < 4; ++r) {
                int t = wband * 32 + m * 16 + g * 4 + r;
                int e = n * 16 + ln;
                size_t oa = ((size_t)((b * SS + s0 + t) * HH + h)) * DD + e;
                out[oa] = O[m][n][r] * inv[r];
            }
    }
}

extern "C" void kernel_launch(void* const* d_in, const int* in_sizes, int n_in,
                              void* d_out, int out_size, void* d_ws, size_t ws_size,
                              hipStream_t stream) {
    const float* qk = (const float*)d_in[0];
    const float* v  = (const float*)d_in[1];
    float* outp = (float*)d_out;

    char* st = (char*)d_ws;
    unsigned short* kbg = (unsigned short*)((char*)d_ws + WS_KB);
    unsigned short* vtg = (unsigned short*)((char*)d_ws + WS_VT);

    prep_state<<<NCHUNK, 256, 0, stream>>>(qk, v, st, kbg, vtg);
    lin_attn_out<<<NCHUNK, 256, 0, stream>>>(qk, kbg, vtg, st, outp);
}

// Round 8
// 37.406 us; speedup vs baseline: 1.0042x; 1.0042x over previous
//
#include <hip/hip_runtime.h>

// Causal linear attention (ELU+1), B=2 S=2048 H=16 D=64.
// Blocks of 128 rows; chunk STATES at 64-row granularity (hierarchical):
// K1 prep_state: stage k,v -> bf16 swizzled exports + TWO 64-states per block via MFMA.
// K2 chunk_scan: exclusive prefix over 32 states/bh -> s0 bf16 swizzled + kz fp32.
// K3 lin_attn_out: per wave = one 32-row band of one 64-chunk; Q*S0 + <=2 causal s-blocks.

#define BB 2
#define SS 2048
#define HH 16
#define DD 64
#define NBLK 512               // 128-row blocks
#define ST64 8448LL            // per-64-chunk blob: 8192B bf16 state + 256B fp32 kz

#define WS_KB (1024LL * ST64)               // kbg after st (1024 64-chunk states)
#define WS_VT (WS_KB + 512LL * 16384)       // vtg
#define WS_S0 (WS_VT + 512LL * 16384)       // s0g bf16 swizzled (1024 x 8192)
#define WS_KZ (WS_S0 + 1024LL * 8192)       // kzg fp32 prefix (1024 x 64 floats)

typedef __attribute__((ext_vector_type(8))) short bf16x8;
typedef __attribute__((ext_vector_type(4))) short bf16x4;
typedef __attribute__((ext_vector_type(4))) float f32x4;

__device__ __forceinline__ float phi(float x) {
    return x > 0.f ? x + 1.f : __expf(x);
}
__device__ __forceinline__ unsigned short f2bf(float x) {
    unsigned int u = __float_as_uint(x);
    u += 0x7fffu + ((u >> 16) & 1u);
    return (unsigned short)(u >> 16);
}
__device__ __forceinline__ float bf2f(unsigned short b) {
    return __uint_as_float(((unsigned int)b) << 16);
}
__device__ __forceinline__ void gload16(const void* g, void* lds) {
    __builtin_amdgcn_global_load_lds(
        (const __attribute__((address_space(1))) unsigned int*)g,
        (__attribute__((address_space(3))) unsigned int*)lds, 16, 0, 0);
}

// ---------------- Kernel 1: prep + two 64-states per block ----------------
__global__ __launch_bounds__(256, 4)
void prep_state(const float* __restrict__ qk, const float* __restrict__ v,
                char* __restrict__ st, unsigned short* __restrict__ kbg,
                unsigned short* __restrict__ vtg) {
    __shared__ unsigned short Kt[DD][136];   // [d][s] phi(k)
    __shared__ unsigned short Vt[DD][136];   // [e][s] v

    const int tid = threadIdx.x, blk = blockIdx.x;
    const int bh = blk >> 4, j = blk & 15, b = bh / HH, h = bh % HH;
    const int s0 = j * 128;
    const int lr = tid >> 4, lc = (tid & 15) * 4;
    char* kbc = (char*)kbg + (size_t)blk * 16384;

    #pragma unroll
    for (int it = 0; it < 8; ++it) {
        int row = it * 16 + lr;
        size_t ka = ((size_t)((b * SS + s0 + row) * 2 + 1)) * (HH * DD) + h * DD + lc;
        float4 kv = *(const float4*)(qk + ka);
        ushort4 kq = make_ushort4(f2bf(phi(kv.x)), f2bf(phi(kv.y)),
                                  f2bf(phi(kv.z)), f2bf(phi(kv.w)));
        *(ushort4*)(kbc + row * 128 + ((lc * 2) ^ ((row & 7) << 4))) = kq;
        Kt[lc + 0][row] = kq.x; Kt[lc + 1][row] = kq.y;
        Kt[lc + 2][row] = kq.z; Kt[lc + 3][row] = kq.w;
        size_t va = ((size_t)((b * SS + s0 + row) * HH + h)) * DD + lc;
        float4 vv = *(const float4*)(v + va);
        Vt[lc + 0][row] = f2bf(vv.x); Vt[lc + 1][row] = f2bf(vv.y);
        Vt[lc + 2][row] = f2bf(vv.z); Vt[lc + 3][row] = f2bf(vv.w);
    }
    __syncthreads();

    // export V^T (swizzled 256B rows)
    {
        char* vtc = (char*)vtg + (size_t)blk * 16384;
        int e = tid >> 2, sq = (tid & 3) * 32;
        #pragma unroll
        for (int k8 = 0; k8 < 4; ++k8) {
            int s = sq + k8 * 8;
            bf16x8 val = *(const bf16x8*)&Vt[e][s];
            *(bf16x8*)(vtc + e * 256 + ((s * 2) ^ ((e & 7) << 4))) = val;
        }
    }

    // MFMA: two 64-states; stateX[e][d] = sum_s V[s][e] K[s][d]; kz via ones-A (wave 0)
    const int w = tid >> 6, lane = tid & 63, g = lane >> 4, ln = lane & 15;
    {
        bf16x8 av[4];
        #pragma unroll
        for (int ks = 0; ks < 4; ++ks)
            av[ks] = *(const bf16x8*)&Vt[w * 16 + ln][ks * 32 + g * 8];
        bf16x8 ones;
        #pragma unroll
        for (int jj = 0; jj < 8; ++jj) ones[jj] = (short)0x3F80;

        char* stc0 = st + (size_t)(blk * 2 + 0) * ST64;
        char* stc1 = st + (size_t)(blk * 2 + 1) * ST64;
        #pragma unroll
        for (int n = 0; n < 4; ++n) {
            f32x4 aA = {0.f, 0.f, 0.f, 0.f}, aB = {0.f, 0.f, 0.f, 0.f};
            f32x4 kzA = {0.f, 0.f, 0.f, 0.f}, kzB = {0.f, 0.f, 0.f, 0.f};
            bf16x8 bk0 = *(const bf16x8*)&Kt[n * 16 + ln][0 * 32 + g * 8];
            bf16x8 bk1 = *(const bf16x8*)&Kt[n * 16 + ln][1 * 32 + g * 8];
            bf16x8 bk2 = *(const bf16x8*)&Kt[n * 16 + ln][2 * 32 + g * 8];
            bf16x8 bk3 = *(const bf16x8*)&Kt[n * 16 + ln][3 * 32 + g * 8];
            aA = __builtin_amdgcn_mfma_f32_16x16x32_bf16(av[0], bk0, aA, 0, 0, 0);
            aA = __builtin_amdgcn_mfma_f32_16x16x32_bf16(av[1], bk1, aA, 0, 0, 0);
            aB = __builtin_amdgcn_mfma_f32_16x16x32_bf16(av[2], bk2, aB, 0, 0, 0);
            aB = __builtin_amdgcn_mfma_f32_16x16x32_bf16(av[3], bk3, aB, 0, 0, 0);
            if (w == 0) {
                kzA = __builtin_amdgcn_mfma_f32_16x16x32_bf16(ones, bk0, kzA, 0, 0, 0);
                kzA = __builtin_amdgcn_mfma_f32_16x16x32_bf16(ones, bk1, kzA, 0, 0, 0);
                kzB = __builtin_amdgcn_mfma_f32_16x16x32_bf16(ones, bk2, kzB, 0, 0, 0);
                kzB = __builtin_amdgcn_mfma_f32_16x16x32_bf16(ones, bk3, kzB, 0, 0, 0);
            }
            #pragma unroll
            for (int r = 0; r < 4; ++r) {
                int off = (((w * 16 + g * 4 + r) * 64) + n * 16 + ln) * 2;
                *(unsigned short*)(stc0 + off) = f2bf(aA[r]);
                *(unsigned short*)(stc1 + off) = f2bf(aB[r]);
            }
            if (w == 0 && g == 0) {
                *(float*)(stc0 + 8192 + (n * 16 + ln) * 4) = kzA[0];
                *(float*)(stc1 + 8192 + (n * 16 + ln) * 4) = kzB[0];
            }
        }
    }
}

// ---------------- Kernel 2: exclusive prefix over 32 states per bh ----------------
__global__ __launch_bounds__(256)
void chunk_scan(const char* __restrict__ st, unsigned short* __restrict__ s0g,
                float* __restrict__ kzg) {
    int flat = blockIdx.x * 256 + threadIdx.x;   // 130*256 = 33280 = 32*1040
    int bh = flat / 1040, i = flat % 1040;
    const char* stb = st + (size_t)(bh * 32) * ST64;
    if (i < 1024) {
        int i4 = i * 4, e = i4 >> 6, d = i4 & 63;
        const char* src = stb + i * 8;
        char* dst = (char*)s0g + (size_t)(bh * 32) * 8192
                    + e * 128 + ((d * 2) ^ ((e & 7) << 4));
        float4 run = {0.f, 0.f, 0.f, 0.f};
        #pragma unroll
        for (int cc = 0; cc < 32; ++cc) {
            *(ushort4*)(dst + (size_t)cc * 8192) =
                make_ushort4(f2bf(run.x), f2bf(run.y), f2bf(run.z), f2bf(run.w));
            ushort4 x = *(const ushort4*)(src + (size_t)cc * ST64);
            run.x += bf2f(x.x); run.y += bf2f(x.y);
            run.z += bf2f(x.z); run.w += bf2f(x.w);
        }
    } else {
        int jj = (i - 1024) * 4;   // 0..60
        const char* src = stb + 8192 + jj * 4;
        float* dst = kzg + (size_t)(bh * 32) * 64 + jj;
        float4 run = {0.f, 0.f, 0.f, 0.f};
        #pragma unroll
        for (int cc = 0; cc < 32; ++cc) {
            *(float4*)(dst + (size_t)cc * 64) = run;
            float4 x = *(const float4*)(src + (size_t)cc * ST64);
            run.x += x.x; run.y += x.y; run.z += x.z; run.w += x.w;
        }
    }
}

// ---------------- Kernel 3: per-block output via MFMA ----------------
__global__ __launch_bounds__(256, 2)
void lin_attn_out(const float* __restrict__ qk,
                  const unsigned short* __restrict__ kbg,
                  const unsigned short* __restrict__ vtg,
                  const unsigned short* __restrict__ s0g,
                  const float* __restrict__ kzg,
                  float* __restrict__ out) {
    __shared__ __align__(16) char KbL[16384];            // [s][d] swizzled (128 rows)
    __shared__ __align__(16) char VtL[16384];            // [e][s] swizzled
    __shared__ __align__(16) char S0L[16384];            // two [e][d] swizzled states
    __shared__ float kzl[128];                           // two kz vectors
    __shared__ __align__(16) unsigned short Wl[4][32][44];
    __shared__ float nul[4][32];

    const int tid = threadIdx.x, blk = blockIdx.x;
    const int bh = blk >> 4, j = blk & 15, b = bh / HH, h = bh % HH;
    const int rb = j * 128;
    const int w = tid >> 6, lane = tid & 63, g = lane >> 4, ln = lane & 15;
    const int flip = (blk >> 8) & 1;     // co-resident pairs are blk, blk+256
    const int ch = w >> 1;               // which 64-chunk of this block
    const int bnd = (w & 1) ^ flip;      // 32-row band within the chunk (0 or 1)

    // async stage K, V^T, two S0 states
    {
        const char* kbs = (const char*)kbg + (size_t)blk * 16384;
        const char* vts = (const char*)vtg + (size_t)blk * 16384;
        const char* s0s = (const char*)s0g + (size_t)(bh * 32 + j * 2) * 8192;
        #pragma unroll
        for (int i = 0; i < 4; ++i) {
            gload16(kbs + w * 4096 + i * 1024 + lane * 16, KbL + w * 4096 + i * 1024);
            gload16(vts + w * 4096 + i * 1024 + lane * 16, VtL + w * 4096 + i * 1024);
            gload16(s0s + w * 4096 + i * 1024 + lane * 16, S0L + w * 4096 + i * 1024);
        }
        if (tid < 128) kzl[tid] = kzg[(size_t)(bh * 32 + j * 2) * 64 + tid];
    }

    // q -> registers (phi + bf16)
    bf16x8 aq[2][2];
    #pragma unroll
    for (int m = 0; m < 2; ++m) {
        int tg = rb + ch * 64 + bnd * 32 + m * 16 + ln;
        const float* qrow = qk + ((size_t)((b * SS + tg) * 2)) * (HH * DD) + h * DD;
        #pragma unroll
        for (int kb2 = 0; kb2 < 2; ++kb2) {
            float4 x0 = *(const float4*)(qrow + kb2 * 32 + g * 8);
            float4 x1 = *(const float4*)(qrow + kb2 * 32 + g * 8 + 4);
            bf16x8 f;
            f[0] = (short)f2bf(phi(x0.x)); f[1] = (short)f2bf(phi(x0.y));
            f[2] = (short)f2bf(phi(x0.z)); f[3] = (short)f2bf(phi(x0.w));
            f[4] = (short)f2bf(phi(x1.x)); f[5] = (short)f2bf(phi(x1.y));
            f[6] = (short)f2bf(phi(x1.z)); f[7] = (short)f2bf(phi(x1.w));
            aq[m][kb2] = f;
        }
    }
    __syncthreads();

    f32x4 O[2][4];
    #pragma unroll
    for (int m = 0; m < 2; ++m)
        #pragma unroll
        for (int n = 0; n < 4; ++n) O[m][n] = (f32x4){0.f, 0.f, 0.f, 0.f};

    // inter-chunk: O += Q * S0[ch]
    const char* S0c = S0L + ch * 8192;
    #pragma unroll
    for (int n = 0; n < 4; ++n) {
        int e = n * 16 + ln;
        bf16x8 b0 = *(const bf16x8*)(S0c + e * 128 + ((g * 16) ^ ((e & 7) << 4)));
        bf16x8 b1 = *(const bf16x8*)(S0c + e * 128 + ((64 + g * 16) ^ ((e & 7) << 4)));
        #pragma unroll
        for (int m = 0; m < 2; ++m) {
            O[m][n] = __builtin_amdgcn_mfma_f32_16x16x32_bf16(aq[m][0], b0, O[m][n], 0, 0, 0);
            O[m][n] = __builtin_amdgcn_mfma_f32_16x16x32_bf16(aq[m][1], b1, O[m][n], 0, 0, 0);
        }
    }

    // nu base: q . kz[ch]
    float nuA[2] = {0.f, 0.f};
    #pragma unroll
    for (int kb2 = 0; kb2 < 2; ++kb2)
        #pragma unroll
        for (int jj = 0; jj < 8; ++jj) {
            float kzv = kzl[ch * 64 + kb2 * 32 + g * 8 + jj];
            nuA[0] = fmaf(bf2f((unsigned short)aq[0][kb2][jj]), kzv, nuA[0]);
            nuA[1] = fmaf(bf2f((unsigned short)aq[1][kb2][jj]), kzv, nuA[1]);
        }

    // causal s-block loop within this 64-chunk (bnd+1 iterations, <=2)
    for (int sblk = 0; sblk <= bnd; ++sblk) {
        const bool diag = (sblk == bnd);
        f32x4 Sc[2][2];
        #pragma unroll
        for (int m = 0; m < 2; ++m)
            #pragma unroll
            for (int ns = 0; ns < 2; ++ns) Sc[m][ns] = (f32x4){0.f, 0.f, 0.f, 0.f};

        #pragma unroll
        for (int ns = 0; ns < 2; ++ns) {
            int s = ch * 64 + sblk * 32 + ns * 16 + ln;
            const char* srow = KbL + s * 128;
            bf16x8 bk0 = *(const bf16x8*)(srow + ((g * 16) ^ ((s & 7) << 4)));
            bf16x8 bk1 = *(const bf16x8*)(srow + ((64 + g * 16) ^ ((s & 7) << 4)));
            #pragma unroll
            for (int m = 0; m < 2; ++m) {
                Sc[m][ns] = __builtin_amdgcn_mfma_f32_16x16x32_bf16(aq[m][0], bk0, Sc[m][ns], 0, 0, 0);
                Sc[m][ns] = __builtin_amdgcn_mfma_f32_16x16x32_bf16(aq[m][1], bk1, Sc[m][ns], 0, 0, 0);
            }
        }

        // mask + bounce (f32 C-layout -> bf16 A-layout), Wl padded to 44
        #pragma unroll
        for (int m = 0; m < 2; ++m)
            #pragma unroll
            for (int ns = 0; ns < 2; ++ns)
                #pragma unroll
                for (int r = 0; r < 4; ++r) {
                    int t_loc = m * 16 + g * 4 + r;
                    int s_loc = ns * 16 + ln;
                    float val = Sc[m][ns][r];
                    if (diag && s_loc > t_loc) val = 0.f;
                    Wl[w][t_loc][s_loc] = f2bf(val);
                }
        asm volatile("s_waitcnt lgkmcnt(0)" ::: "memory");
        __builtin_amdgcn_sched_barrier(0);

        bf16x8 bv[4];
        #pragma unroll
        for (int n = 0; n < 4; ++n) {
            int e = n * 16 + ln;
            bv[n] = *(const bf16x8*)(VtL + e * 256
                        + ((((ch * 2 + sblk) * 64) + g * 16) ^ ((e & 7) << 4)));
        }

        #pragma unroll
        for (int m = 0; m < 2; ++m) {
            const unsigned short* prow = &Wl[w][m * 16 + ln][0];
            bf16x4 plo = *(const bf16x4*)(prow + g * 8);
            bf16x4 phi2 = *(const bf16x4*)(prow + g * 8 + 4);
            bf16x8 pa = __builtin_shufflevector(plo, phi2, 0, 1, 2, 3, 4, 5, 6, 7);
            float rs = 0.f;
            #pragma unroll
            for (int jj = 0; jj < 8; ++jj) rs += bf2f((unsigned short)pa[jj]);
            nuA[m] += rs;
            #pragma unroll
            for (int n = 0; n < 4; ++n)
                O[m][n] = __builtin_amdgcn_mfma_f32_16x16x32_bf16(pa, bv[n], O[m][n], 0, 0, 0);
        }
    }

    // nu reduce + normalize + store
    #pragma unroll
    for (int m = 0; m < 2; ++m) {
        float nt = nuA[m];
        nt += __shfl_xor(nt, 16);
        nt += __shfl_xor(nt, 32);
        if (g == 0) nul[w][m * 16 + ln] = nt;
    }
    asm volatile("s_waitcnt lgkmcnt(0)" ::: "memory");
    __builtin_amdgcn_sched_barrier(0);

    #pragma unroll
    for (int m = 0; m < 2; ++m) {
        float inv[4];
        #pragma unroll
        for (int r = 0; r < 4; ++r) inv[r] = 1.f / nul[w][m * 16 + g * 4 + r];
        #pragma unroll
        for (int n = 0; n < 4; ++n)
            #pragma unroll
            for (int r = 0; r < 4; ++r) {
                int t = ch * 64 + bnd * 32 + m * 16 + g * 4 + r;
                int e = n * 16 + ln;
                size_t oa = ((size_t)((b * SS + rb + t) * HH + h)) * DD + e;
                out[oa] = O[m][n][r] * inv[r];
            }
    }
}

extern "C" void kernel_launch(void* const* d_in, const int* in_sizes, int n_in,
                              void* d_out, int out_size, void* d_ws, size_t ws_size,
                              hipStream_t stream) {
    const float* qk = (const float*)d_in[0];
    const float* v  = (const float*)d_in[1];
    float* outp = (float*)d_out;

    char* st = (char*)d_ws;
    unsigned short* kbg = (unsigned short*)((char*)d_ws + WS_KB);
    unsigned short* vtg = (unsigned short*)((char*)d_ws + WS_VT);
    unsigned short* s0g = (unsigned short*)((char*)d_ws + WS_S0);
    float* kzg = (float*)((char*)d_ws + WS_KZ);

    prep_state<<<NBLK, 256, 0, stream>>>(qk, v, st, kbg, vtg);
    chunk_scan<<<130, 256, 0, stream>>>(st, s0g, kzg);
    lin_attn_out<<<NBLK, 256, 0, stream>>>(qk, kbg, vtg, s0g, kzg, outp);
}

// Round 9
// 36.391 us; speedup vs baseline: 1.0322x; 1.0279x over previous
//
#include <hip/hip_runtime.h>

// Causal linear attention (ELU+1), B=2 S=2048 H=16 D=64, chunk C=128.
// K1 prep_state: stage k,v -> bf16 swizzled exports + per-chunk state (bf16+kz) via MFMA.
// K3 lin_attn_out: ILP'd prefix-scan prologue (st, L2-local via XCD swizzle) -> S0L/kzl;
//                  MFMA QK^T -> LDS bounce -> W.V ; Q.S0 ; normalize.

#define BB 2
#define SS 2048
#define HH 16
#define DD 64
#define CC 128
#define NC (SS / CC)           // 16
#define BH (BB * HH)           // 32
#define NCHUNK (BH * NC)       // 512

#define ST_STRIDE 8448LL       // bytes: 4096 bf16 state + 64 fp32 kz
#define WS_KB (512LL * ST_STRIDE)           // kbg
#define WS_VT (WS_KB + 512LL * 16384)       // vtg

typedef __attribute__((ext_vector_type(8))) short bf16x8;
typedef __attribute__((ext_vector_type(4))) float f32x4;

__device__ __forceinline__ float phi(float x) {
    return x > 0.f ? x + 1.f : __expf(x);
}
__device__ __forceinline__ unsigned short f2bf(float x) {
    unsigned int u = __float_as_uint(x);
    u += 0x7fffu + ((u >> 16) & 1u);
    return (unsigned short)(u >> 16);
}
__device__ __forceinline__ float bf2f(unsigned short b) {
    return __uint_as_float(((unsigned int)b) << 16);
}
__device__ __forceinline__ void gload16(const void* g, void* lds) {
    __builtin_amdgcn_global_load_lds(
        (const __attribute__((address_space(1))) unsigned int*)g,
        (__attribute__((address_space(3))) unsigned int*)lds, 16, 0, 0);
}
// XCD-locality swizzle: hw blocks with hw%8==x run on XCD x; give each XCD a
// contiguous 64-block (4-bh) slice so same-bh blocks share one L2.
__device__ __forceinline__ int xswz(int hw) {
    return ((hw & 7) << 6) | (hw >> 3);
}

// ---------------- Kernel 1: prep + per-chunk state ----------------
__global__ __launch_bounds__(256, 4)
void prep_state(const float* __restrict__ qk, const float* __restrict__ v,
                char* __restrict__ st, unsigned short* __restrict__ kbg,
                unsigned short* __restrict__ vtg) {
    __shared__ unsigned short Kt[DD][136];   // [d][s] phi(k)
    __shared__ unsigned short Vt[DD][136];   // [e][s] v

    const int tid = threadIdx.x, blk = xswz(blockIdx.x);
    const int bh = blk / NC, c = blk % NC, b = bh / HH, h = bh % HH;
    const int s0 = c * CC;
    const int lr = tid >> 4, lc = (tid & 15) * 4;
    char* kbc = (char*)kbg + (size_t)blk * 16384;

    #pragma unroll
    for (int it = 0; it < 8; ++it) {
        int row = it * 16 + lr;
        size_t ka = ((size_t)((b * SS + s0 + row) * 2 + 1)) * (HH * DD) + h * DD + lc;
        float4 kv = *(const float4*)(qk + ka);
        ushort4 kq = make_ushort4(f2bf(phi(kv.x)), f2bf(phi(kv.y)),
                                  f2bf(phi(kv.z)), f2bf(phi(kv.w)));
        *(ushort4*)(kbc + row * 128 + ((lc * 2) ^ ((row & 7) << 4))) = kq;
        Kt[lc + 0][row] = kq.x; Kt[lc + 1][row] = kq.y;
        Kt[lc + 2][row] = kq.z; Kt[lc + 3][row] = kq.w;
        size_t va = ((size_t)((b * SS + s0 + row) * HH + h)) * DD + lc;
        float4 vv = *(const float4*)(v + va);
        Vt[lc + 0][row] = f2bf(vv.x); Vt[lc + 1][row] = f2bf(vv.y);
        Vt[lc + 2][row] = f2bf(vv.z); Vt[lc + 3][row] = f2bf(vv.w);
    }
    __syncthreads();

    // export V^T (swizzled 256B rows)
    {
        char* vtc = (char*)vtg + (size_t)blk * 16384;
        int e = tid >> 2, sq = (tid & 3) * 32;
        #pragma unroll
        for (int k8 = 0; k8 < 4; ++k8) {
            int s = sq + k8 * 8;
            bf16x8 val = *(const bf16x8*)&Vt[e][s];
            *(bf16x8*)(vtc + e * 256 + ((s * 2) ^ ((e & 7) << 4))) = val;
        }
    }

    // MFMA: state[e][d] = sum_s V[s][e] K[s][d]; kz[d] via ones-A (wave 0)
    const int w = tid >> 6, lane = tid & 63, g = lane >> 4, ln = lane & 15;
    {
        bf16x8 av[4];
        #pragma unroll
        for (int ks = 0; ks < 4; ++ks)
            av[ks] = *(const bf16x8*)&Vt[w * 16 + ln][ks * 32 + g * 8];
        bf16x8 ones;
        #pragma unroll
        for (int j = 0; j < 8; ++j) ones[j] = (short)0x3F80;

        char* stc = st + (size_t)blk * ST_STRIDE;
        #pragma unroll
        for (int n = 0; n < 4; ++n) {
            f32x4 a = {0.f, 0.f, 0.f, 0.f}, kz4 = {0.f, 0.f, 0.f, 0.f};
            #pragma unroll
            for (int ks = 0; ks < 4; ++ks) {
                bf16x8 bk = *(const bf16x8*)&Kt[n * 16 + ln][ks * 32 + g * 8];
                a = __builtin_amdgcn_mfma_f32_16x16x32_bf16(av[ks], bk, a, 0, 0, 0);
                if (w == 0)
                    kz4 = __builtin_amdgcn_mfma_f32_16x16x32_bf16(ones, bk, kz4, 0, 0, 0);
            }
            #pragma unroll
            for (int r = 0; r < 4; ++r)
                *(unsigned short*)(stc + (((w * 16 + g * 4 + r) * 64) + n * 16 + ln) * 2)
                    = f2bf(a[r]);
            if (w == 0 && g == 0)
                *(float*)(stc + 8192 + (n * 16 + ln) * 4) = kz4[0];
        }
    }
}

// ---------------- Kernel 3: scan prologue + output via MFMA ----------------
__global__ __launch_bounds__(256, 2)
void lin_attn_out(const float* __restrict__ qk,
                  const unsigned short* __restrict__ kbg,
                  const unsigned short* __restrict__ vtg,
                  const char* __restrict__ st,
                  float* __restrict__ out) {
    __shared__ __align__(16) char KbL[16384];            // [s][d] swizzled
    __shared__ __align__(16) char VtL[16384];            // [e][s] swizzled
    __shared__ __align__(16) char S0L[8192];             // [e][d] swizzled
    __shared__ float kzl[DD];
    __shared__ __align__(16) unsigned short Wl[4][32][40];
    __shared__ float nul[4][32];

    const int tid = threadIdx.x, blk = xswz(blockIdx.x);
    const int bh = blk / NC, c = blk % NC, b = bh / HH, h = bh % HH;
    const int s0 = c * CC;
    const int w = tid >> 6, lane = tid & 63, g = lane >> 4, ln = lane & 15;
    const int wband = ((blk >> 5) & 1) ? (3 - w) : w;  // co-resident pair differs in bit5

    // async stage K, V^T
    {
        const char* kbs = (const char*)kbg + (size_t)blk * 16384;
        const char* vts = (const char*)vtg + (size_t)blk * 16384;
        #pragma unroll
        for (int i = 0; i < 4; ++i) {
            gload16(kbs + w * 4096 + i * 1024 + lane * 16, KbL + w * 4096 + i * 1024);
            gload16(vts + w * 4096 + i * 1024 + lane * 16, VtL + w * 4096 + i * 1024);
        }
    }

    // prologue: prefix-sum of this bh's chunk states (< c) -> S0L swizzled + kzl
    {
        const char* stb = st + (size_t)bh * NC * ST_STRIDE;
        const char* src = stb + tid * 32;
        float accA[16], accB[16];
        #pragma unroll
        for (int j = 0; j < 16; ++j) { accA[j] = 0.f; accB[j] = 0.f; }
        int c2 = 0;
        for (; c2 + 2 <= c; c2 += 2) {
            bf16x8 xa0 = *(const bf16x8*)(src + (size_t)c2 * ST_STRIDE);
            bf16x8 xa1 = *(const bf16x8*)(src + (size_t)c2 * ST_STRIDE + 16);
            bf16x8 xb0 = *(const bf16x8*)(src + (size_t)(c2 + 1) * ST_STRIDE);
            bf16x8 xb1 = *(const bf16x8*)(src + (size_t)(c2 + 1) * ST_STRIDE + 16);
            #pragma unroll
            for (int j = 0; j < 8; ++j) {
                accA[j]     += bf2f((unsigned short)xa0[j]);
                accA[j + 8] += bf2f((unsigned short)xa1[j]);
                accB[j]     += bf2f((unsigned short)xb0[j]);
                accB[j + 8] += bf2f((unsigned short)xb1[j]);
            }
        }
        if (c2 < c) {
            bf16x8 xa0 = *(const bf16x8*)(src + (size_t)c2 * ST_STRIDE);
            bf16x8 xa1 = *(const bf16x8*)(src + (size_t)c2 * ST_STRIDE + 16);
            #pragma unroll
            for (int j = 0; j < 8; ++j) {
                accA[j]     += bf2f((unsigned short)xa0[j]);
                accA[j + 8] += bf2f((unsigned short)xa1[j]);
            }
        }
        int e = tid >> 2, d0 = (tid & 3) * 16;
        bf16x8 o0, o1;
        #pragma unroll
        for (int j = 0; j < 8; ++j) {
            o0[j] = (short)f2bf(accA[j] + accB[j]);
            o1[j] = (short)f2bf(accA[j + 8] + accB[j + 8]);
        }
        int sw = (e & 7) << 4;
        *(bf16x8*)(S0L + e * 128 + ((2 * d0) ^ sw)) = o0;
        *(bf16x8*)(S0L + e * 128 + ((2 * d0 + 16) ^ sw)) = o1;

        // kz: 4 interleaved chains per element, reduced via shfl
        int chain = tid & 3;
        float a = 0.f;
        for (int cc = chain; cc < c; cc += 4)
            a += *(const float*)(stb + (size_t)cc * ST_STRIDE + 8192 + 4 * e);
        a += __shfl_xor(a, 1);
        a += __shfl_xor(a, 2);
        if (chain == 0) kzl[e] = a;
    }

    // q -> registers (phi + bf16)
    bf16x8 aq[2][2];
    #pragma unroll
    for (int m = 0; m < 2; ++m) {
        int tg = s0 + wband * 32 + m * 16 + ln;
        const float* qrow = qk + ((size_t)((b * SS + tg) * 2)) * (HH * DD) + h * DD;
        #pragma unroll
        for (int kb2 = 0; kb2 < 2; ++kb2) {
            float4 x0 = *(const float4*)(qrow + kb2 * 32 + g * 8);
            float4 x1 = *(const float4*)(qrow + kb2 * 32 + g * 8 + 4);
            bf16x8 f;
            f[0] = (short)f2bf(phi(x0.x)); f[1] = (short)f2bf(phi(x0.y));
            f[2] = (short)f2bf(phi(x0.z)); f[3] = (short)f2bf(phi(x0.w));
            f[4] = (short)f2bf(phi(x1.x)); f[5] = (short)f2bf(phi(x1.y));
            f[6] = (short)f2bf(phi(x1.z)); f[7] = (short)f2bf(phi(x1.w));
            aq[m][kb2] = f;
        }
    }
    __syncthreads();

    f32x4 O[2][4];
    #pragma unroll
    for (int m = 0; m < 2; ++m)
        #pragma unroll
        for (int n = 0; n < 4; ++n) O[m][n] = (f32x4){0.f, 0.f, 0.f, 0.f};

    // inter-chunk: O += Q * S0
    #pragma unroll
    for (int n = 0; n < 4; ++n) {
        int e = n * 16 + ln;
        bf16x8 b0 = *(const bf16x8*)(S0L + e * 128 + ((g * 16) ^ ((e & 7) << 4)));
        bf16x8 b1 = *(const bf16x8*)(S0L + e * 128 + ((64 + g * 16) ^ ((e & 7) << 4)));
        #pragma unroll
        for (int m = 0; m < 2; ++m) {
            O[m][n] = __builtin_amdgcn_mfma_f32_16x16x32_bf16(aq[m][0], b0, O[m][n], 0, 0, 0);
            O[m][n] = __builtin_amdgcn_mfma_f32_16x16x32_bf16(aq[m][1], b1, O[m][n], 0, 0, 0);
        }
    }

    // nu base: q . kz
    float nuA[2] = {0.f, 0.f};
    #pragma unroll
    for (int kb2 = 0; kb2 < 2; ++kb2)
        #pragma unroll
        for (int j = 0; j < 8; ++j) {
            float kzv = kzl[kb2 * 32 + g * 8 + j];
            nuA[0] = fmaf(bf2f((unsigned short)aq[0][kb2][j]), kzv, nuA[0]);
            nuA[1] = fmaf(bf2f((unsigned short)aq[1][kb2][j]), kzv, nuA[1]);
        }

    // causal s-block loop over this wave's band
    for (int sblk = 0; sblk <= wband; ++sblk) {
        const bool diag = (sblk == wband);
        f32x4 Sc[2][2];
        #pragma unroll
        for (int m = 0; m < 2; ++m)
            #pragma unroll
            for (int ns = 0; ns < 2; ++ns) Sc[m][ns] = (f32x4){0.f, 0.f, 0.f, 0.f};

        #pragma unroll
        for (int ns = 0; ns < 2; ++ns) {
            int s = sblk * 32 + ns * 16 + ln;
            const char* srow = KbL + s * 128;
            bf16x8 bk0 = *(const bf16x8*)(srow + ((g * 16) ^ ((s & 7) << 4)));
            bf16x8 bk1 = *(const bf16x8*)(srow + ((64 + g * 16) ^ ((s & 7) << 4)));
            #pragma unroll
            for (int m = 0; m < 2; ++m) {
                Sc[m][ns] = __builtin_amdgcn_mfma_f32_16x16x32_bf16(aq[m][0], bk0, Sc[m][ns], 0, 0, 0);
                Sc[m][ns] = __builtin_amdgcn_mfma_f32_16x16x32_bf16(aq[m][1], bk1, Sc[m][ns], 0, 0, 0);
            }
        }

        // mask + bounce (f32 C-layout -> bf16 A-layout)
        #pragma unroll
        for (int m = 0; m < 2; ++m)
            #pragma unroll
            for (int ns = 0; ns < 2; ++ns)
                #pragma unroll
                for (int r = 0; r < 4; ++r) {
                    int t_loc = m * 16 + g * 4 + r;
                    int s_loc = ns * 16 + ln;
                    float val = Sc[m][ns][r];
                    if (diag && s_loc > t_loc) val = 0.f;
                    Wl[w][t_loc][s_loc] = f2bf(val);
                }
        asm volatile("s_waitcnt lgkmcnt(0)" ::: "memory");
        __builtin_amdgcn_sched_barrier(0);

        bf16x8 bv[4];
        #pragma unroll
        for (int n = 0; n < 4; ++n) {
            int e = n * 16 + ln;
            bv[n] = *(const bf16x8*)(VtL + e * 256 + ((sblk * 64 + g * 16) ^ ((e & 7) << 4)));
        }

        #pragma unroll
        for (int m = 0; m < 2; ++m) {
            bf16x8 pa = *(const bf16x8*)&Wl[w][m * 16 + ln][g * 8];
            float rs = 0.f;
            #pragma unroll
            for (int j = 0; j < 8; ++j) rs += bf2f((unsigned short)pa[j]);
            nuA[m] += rs;
            #pragma unroll
            for (int n = 0; n < 4; ++n)
                O[m][n] = __builtin_amdgcn_mfma_f32_16x16x32_bf16(pa, bv[n], O[m][n], 0, 0, 0);
        }
    }

    // nu reduce + normalize + store
    #pragma unroll
    for (int m = 0; m < 2; ++m) {
        float nt = nuA[m];
        nt += __shfl_xor(nt, 16);
        nt += __shfl_xor(nt, 32);
        if (g == 0) nul[w][m * 16 + ln] = nt;
    }
    asm volatile("s_waitcnt lgkmcnt(0)" ::: "memory");
    __builtin_amdgcn_sched_barrier(0);

    #pragma unroll
    for (int m = 0; m < 2; ++m) {
        float inv[4];
        #pragma unroll
        for (int r = 0; r < 4; ++r) inv[r] = 1.f / nul[w][m * 16 + g * 4 + r];
        #pragma unroll
        for (int n = 0; n < 4; ++n)
            #pragma unroll
            for (int r = 0; r < 4; ++r) {
                int t = wband * 32 + m * 16 + g * 4 + r;
                int e = n * 16 + ln;
                size_t oa = ((size_t)((b * SS + s0 + t) * HH + h)) * DD + e;
                out[oa] = O[m][n][r] * inv[r];
            }
    }
}

extern "C" void kernel_launch(void* const* d_in, const int* in_sizes, int n_in,
                              void* d_out, int out_size, void* d_ws, size_t ws_size,
                              hipStream_t stream) {
    const float* qk = (const float*)d_in[0];
    const float* v  = (const float*)d_in[1];
    float* outp = (float*)d_out;

    char* st = (char*)d_ws;
    unsigned short* kbg = (unsigned short*)((char*)d_ws + WS_KB);
    unsigned short* vtg = (unsigned short*)((char*)d_ws + WS_VT);

    prep_state<<<NCHUNK, 256, 0, stream>>>(qk, v, st, kbg, vtg);
    lin_attn_out<<<NCHUNK, 256, 0, stream>>>(qk, kbg, vtg, st, outp);
}

// Round 10
// 36.324 us; speedup vs baseline: 1.0341x; 1.0019x over previous
//
#include <hip/hip_runtime.h>

// Causal linear attention (ELU+1), B=2 S=2048 H=16 D=64, chunk C=128.
// K1 prep_state: bf16 phi(k)/v^T export (swizzled) + per-chunk KV^T & kz via MFMA. (R3)
// K2 chunk_scan: exclusive prefix over chunks -> s0 bf16 swizzled + kz fp32.     (R3)
// K3 lin_attn_out: 1024 blocks, 64-row tiles (pipelined rounds), MFMA QK^T/W.V/Q.S0.

#define BB 2
#define SS 2048
#define HH 16
#define DD 64
#define CC 128
#define NC (SS / CC)           // 16
#define BH (BB * HH)           // 32
#define NCHUNK (BH * NC)       // 512
#define STSZ (DD * DD + DD)    // 4160 floats

#define WS_KB (512LL * 4160 * 4)
#define WS_VT (WS_KB + 512LL * 16384)
#define WS_S0 (WS_VT + 512LL * 16384)
#define WS_KZ (WS_S0 + 512LL * 8192)

typedef __attribute__((ext_vector_type(8))) short bf16x8;
typedef __attribute__((ext_vector_type(4))) short bf16x4;
typedef __attribute__((ext_vector_type(4))) float f32x4;

__device__ __forceinline__ float phi(float x) {
    return x > 0.f ? x + 1.f : __expf(x);
}
__device__ __forceinline__ unsigned short f2bf(float x) {
    unsigned int u = __float_as_uint(x);
    u += 0x7fffu + ((u >> 16) & 1u);
    return (unsigned short)(u >> 16);
}
__device__ __forceinline__ float bf2f(unsigned short b) {
    return __uint_as_float(((unsigned int)b) << 16);
}
__device__ __forceinline__ void gload16(const void* g, void* lds) {
    __builtin_amdgcn_global_load_lds(
        (const __attribute__((address_space(1))) unsigned int*)g,
        (__attribute__((address_space(3))) unsigned int*)lds, 16, 0, 0);
}

// ---------------- Kernel 1 (R3) ----------------
__global__ __launch_bounds__(256, 2)
void prep_state(const float* __restrict__ qk, const float* __restrict__ v,
                float* __restrict__ st, unsigned short* __restrict__ kbg,
                unsigned short* __restrict__ vtg) {
    __shared__ unsigned short Kt[DD][136];
    __shared__ unsigned short Vt[DD][136];

    const int tid = threadIdx.x, blk = blockIdx.x;
    const int bh = blk / NC, c = blk % NC, b = bh / HH, h = bh % HH;
    const int s0 = c * CC;
    const int lr = tid >> 4, lc = (tid & 15) * 4;
    char* kbc = (char*)kbg + (size_t)blk * 16384;

    #pragma unroll
    for (int it = 0; it < 8; ++it) {
        int row = it * 16 + lr;
        size_t ka = ((size_t)((b * SS + s0 + row) * 2 + 1)) * (HH * DD) + h * DD + lc;
        float4 kv = *(const float4*)(qk + ka);
        unsigned short k0 = f2bf(phi(kv.x)), k1 = f2bf(phi(kv.y));
        unsigned short k2 = f2bf(phi(kv.z)), k3 = f2bf(phi(kv.w));
        *(ushort4*)(kbc + row * 128 + ((lc * 2) ^ ((row & 7) << 4))) = make_ushort4(k0, k1, k2, k3);
        Kt[lc + 0][row] = k0; Kt[lc + 1][row] = k1;
        Kt[lc + 2][row] = k2; Kt[lc + 3][row] = k3;
        size_t va = ((size_t)((b * SS + s0 + row) * HH + h)) * DD + lc;
        float4 vv = *(const float4*)(v + va);
        Vt[lc + 0][row] = f2bf(vv.x); Vt[lc + 1][row] = f2bf(vv.y);
        Vt[lc + 2][row] = f2bf(vv.z); Vt[lc + 3][row] = f2bf(vv.w);
    }
    __syncthreads();

    {
        char* vtc = (char*)vtg + (size_t)blk * 16384;
        int e = tid >> 2, sq = (tid & 3) * 32;
        #pragma unroll
        for (int k8 = 0; k8 < 4; ++k8) {
            int s = sq + k8 * 8;
            bf16x8 val = *(const bf16x8*)&Vt[e][s];
            *(bf16x8*)(vtc + e * 256 + ((s * 2) ^ ((e & 7) << 4))) = val;
        }
    }

    const int w = tid >> 6, lane = tid & 63, g = lane >> 4, ln = lane & 15;
    bf16x8 av[4];
    #pragma unroll
    for (int ks = 0; ks < 4; ++ks)
        av[ks] = *(const bf16x8*)&Vt[w * 16 + ln][ks * 32 + g * 8];
    bf16x8 ones;
    #pragma unroll
    for (int j = 0; j < 8; ++j) ones[j] = (short)0x3F80;

    float* o = st + (size_t)blk * STSZ;
    #pragma unroll
    for (int n = 0; n < 4; ++n) {
        f32x4 a = {0.f, 0.f, 0.f, 0.f}, kz4 = {0.f, 0.f, 0.f, 0.f};
        #pragma unroll
        for (int ks = 0; ks < 4; ++ks) {
            bf16x8 bk = *(const bf16x8*)&Kt[n * 16 + ln][ks * 32 + g * 8];
            a = __builtin_amdgcn_mfma_f32_16x16x32_bf16(av[ks], bk, a, 0, 0, 0);
            kz4 = __builtin_amdgcn_mfma_f32_16x16x32_bf16(ones, bk, kz4, 0, 0, 0);
        }
        #pragma unroll
        for (int r = 0; r < 4; ++r)
            o[(w * 16 + g * 4 + r) * 64 + n * 16 + ln] = a[r];
        if (w == 0 && g == 0) o[4096 + n * 16 + ln] = kz4[0];
    }
}

// ---------------- Kernel 2 (R3) ----------------
__global__ __launch_bounds__(256)
void chunk_scan(const float* __restrict__ st, unsigned short* __restrict__ s0g,
                float* __restrict__ kzg) {
    int flat = blockIdx.x * 256 + threadIdx.x;   // 130*256 = 33280 = 32*1040
    int bh = flat / 1040, i = flat % 1040;
    if (i < 1024) {
        int i4 = i * 4;
        int e = i4 >> 6, d = i4 & 63;
        const float* src = st + (size_t)(bh * NC) * STSZ + i4;
        char* dst = (char*)s0g + (size_t)(bh * NC) * 8192
                    + e * 128 + ((d * 2) ^ ((e & 7) << 4));
        float4 run = {0.f, 0.f, 0.f, 0.f};
        #pragma unroll
        for (int c2 = 0; c2 < NC; ++c2) {
            *(ushort4*)(dst + (size_t)c2 * 8192) =
                make_ushort4(f2bf(run.x), f2bf(run.y), f2bf(run.z), f2bf(run.w));
            float4 x = *(const float4*)(src + (size_t)c2 * STSZ);
            run.x += x.x; run.y += x.y; run.z += x.z; run.w += x.w;
        }
    } else {
        int j = (i - 1024) * 4;
        const float* src = st + (size_t)(bh * NC) * STSZ + 4096 + j;
        float* dst = kzg + (size_t)(bh * NC) * 64 + j;
        float4 run = {0.f, 0.f, 0.f, 0.f};
        #pragma unroll
        for (int c2 = 0; c2 < NC; ++c2) {
            *(float4*)(dst + (size_t)c2 * 64) = run;
            float4 x = *(const float4*)(src + (size_t)c2 * STSZ);
            run.x += x.x; run.y += x.y; run.z += x.z; run.w += x.w;
        }
    }
}

// ---------------- Kernel 3: 1024 blocks, 64-row tiles ----------------
__global__ __launch_bounds__(256, 3)
void lin_attn_out(const float* __restrict__ qk,
                  const unsigned short* __restrict__ kbg,
                  const unsigned short* __restrict__ vtg,
                  const unsigned short* __restrict__ s0g,
                  const float* __restrict__ kzg,
                  float* __restrict__ out) {
    __shared__ __align__(16) char KbL[16384];            // [s][d] swizzled (full chunk)
    __shared__ __align__(16) char VtL[16384];            // [e][s] swizzled (full chunk)
    __shared__ __align__(16) char S0L[8192];             // [e][d] swizzled
    __shared__ float kzl[DD];
    __shared__ __align__(16) unsigned short Wl[4][16][40];
    __shared__ float nul[4][16];

    const int tid = threadIdx.x, blk = blockIdx.x;
    const int bh = blk >> 5, hc = blk & 31;
    const int c = hc >> 1, half = hc & 1;
    const int b = bh / HH, h = bh % HH;
    const int s0 = c * CC;
    const int ck = bh * NC + c;                  // chunk index into kbg/vtg/s0g/kzg
    const int w = tid >> 6, lane = tid & 63, g = lane >> 4, ln = lane & 15;
    const int T0 = half * 64 + w * 16;           // wave's t-base within chunk

    // async stage K, V^T, S0 (full chunk)
    {
        const char* kbs = (const char*)kbg + (size_t)ck * 16384;
        const char* vts = (const char*)vtg + (size_t)ck * 16384;
        const char* s0s = (const char*)s0g + (size_t)ck * 8192;
        #pragma unroll
        for (int i = 0; i < 4; ++i) {
            gload16(kbs + w * 4096 + i * 1024 + lane * 16, KbL + w * 4096 + i * 1024);
            gload16(vts + w * 4096 + i * 1024 + lane * 16, VtL + w * 4096 + i * 1024);
        }
        #pragma unroll
        for (int i = 0; i < 2; ++i)
            gload16(s0s + w * 2048 + i * 1024 + lane * 16, S0L + w * 2048 + i * 1024);
        if (tid < DD) kzl[tid] = kzg[(size_t)ck * 64 + tid];
    }

    // q -> registers (phi + bf16), one 16-row tile per wave
    bf16x8 aq[2];
    {
        int tg = s0 + T0 + ln;
        const float* qrow = qk + ((size_t)((b * SS + tg) * 2)) * (HH * DD) + h * DD;
        #pragma unroll
        for (int kb2 = 0; kb2 < 2; ++kb2) {
            float4 x0 = *(const float4*)(qrow + kb2 * 32 + g * 8);
            float4 x1 = *(const float4*)(qrow + kb2 * 32 + g * 8 + 4);
            bf16x8 f;
            f[0] = (short)f2bf(phi(x0.x)); f[1] = (short)f2bf(phi(x0.y));
            f[2] = (short)f2bf(phi(x0.z)); f[3] = (short)f2bf(phi(x0.w));
            f[4] = (short)f2bf(phi(x1.x)); f[5] = (short)f2bf(phi(x1.y));
            f[6] = (short)f2bf(phi(x1.z)); f[7] = (short)f2bf(phi(x1.w));
            aq[kb2] = f;
        }
    }
    __syncthreads();

    f32x4 O[4];
    #pragma unroll
    for (int n = 0; n < 4; ++n) O[n] = (f32x4){0.f, 0.f, 0.f, 0.f};

    // inter-chunk: O += Q * S0
    #pragma unroll
    for (int n = 0; n < 4; ++n) {
        int e = n * 16 + ln;
        bf16x8 b0 = *(const bf16x8*)(S0L + e * 128 + ((g * 16) ^ ((e & 7) << 4)));
        bf16x8 b1 = *(const bf16x8*)(S0L + e * 128 + ((64 + g * 16) ^ ((e & 7) << 4)));
        O[n] = __builtin_amdgcn_mfma_f32_16x16x32_bf16(aq[0], b0, O[n], 0, 0, 0);
        O[n] = __builtin_amdgcn_mfma_f32_16x16x32_bf16(aq[1], b1, O[n], 0, 0, 0);
    }

    // nu base: q . kz
    float nuA = 0.f;
    #pragma unroll
    for (int kb2 = 0; kb2 < 2; ++kb2)
        #pragma unroll
        for (int j = 0; j < 8; ++j)
            nuA = fmaf(bf2f((unsigned short)aq[kb2][j]), kzl[kb2 * 32 + g * 8 + j], nuA);

    // causal s-block loop (in-chunk), diag block index = T0/32
    const int dsb = T0 >> 5;
    for (int sb = 0; sb <= dsb; ++sb) {
        const bool diag = (sb == dsb);
        f32x4 Sc[2];
        #pragma unroll
        for (int ns = 0; ns < 2; ++ns) Sc[ns] = (f32x4){0.f, 0.f, 0.f, 0.f};

        #pragma unroll
        for (int ns = 0; ns < 2; ++ns) {
            int s = sb * 32 + ns * 16 + ln;
            const char* srow = KbL + s * 128;
            bf16x8 bk0 = *(const bf16x8*)(srow + ((g * 16) ^ ((s & 7) << 4)));
            bf16x8 bk1 = *(const bf16x8*)(srow + ((64 + g * 16) ^ ((s & 7) << 4)));
            Sc[ns] = __builtin_amdgcn_mfma_f32_16x16x32_bf16(aq[0], bk0, Sc[ns], 0, 0, 0);
            Sc[ns] = __builtin_amdgcn_mfma_f32_16x16x32_bf16(aq[1], bk1, Sc[ns], 0, 0, 0);
        }

        // mask + bounce (f32 C-layout -> bf16 A-layout)
        #pragma unroll
        for (int ns = 0; ns < 2; ++ns)
            #pragma unroll
            for (int r = 0; r < 4; ++r) {
                int t_cr = T0 + g * 4 + r;
                int s_cr = sb * 32 + ns * 16 + ln;
                float val = Sc[ns][r];
                if (diag && s_cr > t_cr) val = 0.f;
                Wl[w][g * 4 + r][ns * 16 + ln] = f2bf(val);
            }
        asm volatile("s_waitcnt lgkmcnt(0)" ::: "memory");
        __builtin_amdgcn_sched_barrier(0);

        bf16x8 bv[4];
        #pragma unroll
        for (int n = 0; n < 4; ++n) {
            int e = n * 16 + ln;
            bv[n] = *(const bf16x8*)(VtL + e * 256 + ((sb * 64 + g * 16) ^ ((e & 7) << 4)));
        }

        {
            const unsigned short* prow = &Wl[w][ln][0];
            bf16x4 plo = *(const bf16x4*)(prow + g * 8);
            bf16x4 phi2 = *(const bf16x4*)(prow + g * 8 + 4);
            bf16x8 pa = __builtin_shufflevector(plo, phi2, 0, 1, 2, 3, 4, 5, 6, 7);
            float rs = 0.f;
            #pragma unroll
            for (int j = 0; j < 8; ++j) rs += bf2f((unsigned short)pa[j]);
            nuA += rs;
            #pragma unroll
            for (int n = 0; n < 4; ++n)
                O[n] = __builtin_amdgcn_mfma_f32_16x16x32_bf16(pa, bv[n], O[n], 0, 0, 0);
        }
    }

    // nu reduce (over g groups) + normalize + store
    {
        float nt = nuA;
        nt += __shfl_xor(nt, 16);
        nt += __shfl_xor(nt, 32);
        if (g == 0) nul[w][ln] = nt;
    }
    asm volatile("s_waitcnt lgkmcnt(0)" ::: "memory");
    __builtin_amdgcn_sched_barrier(0);

    {
        float inv[4];
        #pragma unroll
        for (int r = 0; r < 4; ++r) inv[r] = 1.f / nul[w][g * 4 + r];
        #pragma unroll
        for (int n = 0; n < 4; ++n)
            #pragma unroll
            for (int r = 0; r < 4; ++r) {
                int t = T0 + g * 4 + r;
                int e = n * 16 + ln;
                size_t oa = ((size_t)((b * SS + s0 + t) * HH + h)) * DD + e;
                out[oa] = O[n][r] * inv[r];
            }
    }
}

extern "C" void kernel_launch(void* const* d_in, const int* in_sizes, int n_in,
                              void* d_out, int out_size, void* d_ws, size_t ws_size,
                              hipStream_t stream) {
    const float* qk = (const float*)d_in[0];
    const float* v  = (const float*)d_in[1];
    float* outp = (float*)d_out;

    float* st = (float*)d_ws;
    unsigned short* kbg = (unsigned short*)((char*)d_ws + WS_KB);
    unsigned short* vtg = (unsigned short*)((char*)d_ws + WS_VT);
    unsigned short* s0g = (unsigned short*)((char*)d_ws + WS_S0);
    float* kzg = (float*)((char*)d_ws + WS_KZ);

    prep_state<<<NCHUNK, 256, 0, stream>>>(qk, v, st, kbg, vtg);
    chunk_scan<<<130, 256, 0, stream>>>(st, s0g, kzg);
    lin_attn_out<<<NCHUNK * 2, 256, 0, stream>>>(qk, kbg, vtg, s0g, kzg, outp);
}

// Round 11
// 33.780 us; speedup vs baseline: 1.1120x; 1.0753x over previous
//
#include <hip/hip_runtime.h>

// Causal linear attention (ELU+1), B=2 S=2048 H=16 D=64, chunk C=128.
// K1 prep_state (R3): bf16 phi(k)/v^T export (swizzled) + per-chunk KV^T & kz via MFMA.
// K2 chunk_scan (R3): exclusive prefix over chunks -> s0 bf16 swizzled + kz fp32.
// K3 lin_attn_out: balanced t-tile pairing — wave w owns 16-row tiles {w, 7-w};
//                  every wave does exactly 5 causal s-blocks (was 1..4 imbalanced).

#define BB 2
#define SS 2048
#define HH 16
#define DD 64
#define CC 128
#define NC (SS / CC)           // 16
#define BH (BB * HH)           // 32
#define NCHUNK (BH * NC)       // 512
#define STSZ (DD * DD + DD)    // 4160 floats

#define WS_KB (512LL * 4160 * 4)
#define WS_VT (WS_KB + 512LL * 16384)
#define WS_S0 (WS_VT + 512LL * 16384)
#define WS_KZ (WS_S0 + 512LL * 8192)

typedef __attribute__((ext_vector_type(8))) short bf16x8;
typedef __attribute__((ext_vector_type(4))) float f32x4;

__device__ __forceinline__ float phi(float x) {
    return x > 0.f ? x + 1.f : __expf(x);
}
__device__ __forceinline__ unsigned short f2bf(float x) {
    unsigned int u = __float_as_uint(x);
    u += 0x7fffu + ((u >> 16) & 1u);
    return (unsigned short)(u >> 16);
}
__device__ __forceinline__ float bf2f(unsigned short b) {
    return __uint_as_float(((unsigned int)b) << 16);
}
__device__ __forceinline__ void gload16(const void* g, void* lds) {
    __builtin_amdgcn_global_load_lds(
        (const __attribute__((address_space(1))) unsigned int*)g,
        (__attribute__((address_space(3))) unsigned int*)lds, 16, 0, 0);
}

// ---------------- Kernel 1 (R3) ----------------
__global__ __launch_bounds__(256, 2)
void prep_state(const float* __restrict__ qk, const float* __restrict__ v,
                float* __restrict__ st, unsigned short* __restrict__ kbg,
                unsigned short* __restrict__ vtg) {
    __shared__ unsigned short Kt[DD][136];
    __shared__ unsigned short Vt[DD][136];

    const int tid = threadIdx.x, blk = blockIdx.x;
    const int bh = blk / NC, c = blk % NC, b = bh / HH, h = bh % HH;
    const int s0 = c * CC;
    const int lr = tid >> 4, lc = (tid & 15) * 4;
    char* kbc = (char*)kbg + (size_t)blk * 16384;

    #pragma unroll
    for (int it = 0; it < 8; ++it) {
        int row = it * 16 + lr;
        size_t ka = ((size_t)((b * SS + s0 + row) * 2 + 1)) * (HH * DD) + h * DD + lc;
        float4 kv = *(const float4*)(qk + ka);
        unsigned short k0 = f2bf(phi(kv.x)), k1 = f2bf(phi(kv.y));
        unsigned short k2 = f2bf(phi(kv.z)), k3 = f2bf(phi(kv.w));
        *(ushort4*)(kbc + row * 128 + ((lc * 2) ^ ((row & 7) << 4))) = make_ushort4(k0, k1, k2, k3);
        Kt[lc + 0][row] = k0; Kt[lc + 1][row] = k1;
        Kt[lc + 2][row] = k2; Kt[lc + 3][row] = k3;
        size_t va = ((size_t)((b * SS + s0 + row) * HH + h)) * DD + lc;
        float4 vv = *(const float4*)(v + va);
        Vt[lc + 0][row] = f2bf(vv.x); Vt[lc + 1][row] = f2bf(vv.y);
        Vt[lc + 2][row] = f2bf(vv.z); Vt[lc + 3][row] = f2bf(vv.w);
    }
    __syncthreads();

    {
        char* vtc = (char*)vtg + (size_t)blk * 16384;
        int e = tid >> 2, sq = (tid & 3) * 32;
        #pragma unroll
        for (int k8 = 0; k8 < 4; ++k8) {
            int s = sq + k8 * 8;
            bf16x8 val = *(const bf16x8*)&Vt[e][s];
            *(bf16x8*)(vtc + e * 256 + ((s * 2) ^ ((e & 7) << 4))) = val;
        }
    }

    const int w = tid >> 6, lane = tid & 63, g = lane >> 4, ln = lane & 15;
    bf16x8 av[4];
    #pragma unroll
    for (int ks = 0; ks < 4; ++ks)
        av[ks] = *(const bf16x8*)&Vt[w * 16 + ln][ks * 32 + g * 8];
    bf16x8 ones;
    #pragma unroll
    for (int j = 0; j < 8; ++j) ones[j] = (short)0x3F80;

    float* o = st + (size_t)blk * STSZ;
    #pragma unroll
    for (int n = 0; n < 4; ++n) {
        f32x4 a = {0.f, 0.f, 0.f, 0.f}, kz4 = {0.f, 0.f, 0.f, 0.f};
        #pragma unroll
        for (int ks = 0; ks < 4; ++ks) {
            bf16x8 bk = *(const bf16x8*)&Kt[n * 16 + ln][ks * 32 + g * 8];
            a = __builtin_amdgcn_mfma_f32_16x16x32_bf16(av[ks], bk, a, 0, 0, 0);
            kz4 = __builtin_amdgcn_mfma_f32_16x16x32_bf16(ones, bk, kz4, 0, 0, 0);
        }
        #pragma unroll
        for (int r = 0; r < 4; ++r)
            o[(w * 16 + g * 4 + r) * 64 + n * 16 + ln] = a[r];
        if (w == 0 && g == 0) o[4096 + n * 16 + ln] = kz4[0];
    }
}

// ---------------- Kernel 2 (R3) ----------------
__global__ __launch_bounds__(256)
void chunk_scan(const float* __restrict__ st, unsigned short* __restrict__ s0g,
                float* __restrict__ kzg) {
    int flat = blockIdx.x * 256 + threadIdx.x;   // 130*256 = 33280 = 32*1040
    int bh = flat / 1040, i = flat % 1040;
    if (i < 1024) {
        int i4 = i * 4;
        int e = i4 >> 6, d = i4 & 63;
        const float* src = st + (size_t)(bh * NC) * STSZ + i4;
        char* dst = (char*)s0g + (size_t)(bh * NC) * 8192
                    + e * 128 + ((d * 2) ^ ((e & 7) << 4));
        float4 run = {0.f, 0.f, 0.f, 0.f};
        #pragma unroll
        for (int c2 = 0; c2 < NC; ++c2) {
            *(ushort4*)(dst + (size_t)c2 * 8192) =
                make_ushort4(f2bf(run.x), f2bf(run.y), f2bf(run.z), f2bf(run.w));
            float4 x = *(const float4*)(src + (size_t)c2 * STSZ);
            run.x += x.x; run.y += x.y; run.z += x.z; run.w += x.w;
        }
    } else {
        int j = (i - 1024) * 4;
        const float* src = st + (size_t)(bh * NC) * STSZ + 4096 + j;
        float* dst = kzg + (size_t)(bh * NC) * 64 + j;
        float4 run = {0.f, 0.f, 0.f, 0.f};
        #pragma unroll
        for (int c2 = 0; c2 < NC; ++c2) {
            *(float4*)(dst + (size_t)c2 * 64) = run;
            float4 x = *(const float4*)(src + (size_t)c2 * STSZ);
            run.x += x.x; run.y += x.y; run.z += x.z; run.w += x.w;
        }
    }
}

// ---------------- Kernel 3: balanced t-tile pairing ----------------
__global__ __launch_bounds__(256, 3)
void lin_attn_out(const float* __restrict__ qk,
                  const unsigned short* __restrict__ kbg,
                  const unsigned short* __restrict__ vtg,
                  const unsigned short* __restrict__ s0g,
                  const float* __restrict__ kzg,
                  float* __restrict__ out) {
    __shared__ __align__(16) char KbL[16384];            // [s][d] swizzled
    __shared__ __align__(16) char VtL[16384];            // [e][s] swizzled
    __shared__ __align__(16) char S0L[8192];             // [e][d] swizzled
    __shared__ float kzl[DD];
    __shared__ __align__(16) unsigned short Wl[4][2][16][40];  // per-wave, per-tile bounce
    __shared__ float nul[4][2][16];

    const int tid = threadIdx.x, blk = blockIdx.x;
    const int bh = blk / NC, c = blk % NC, b = bh / HH, h = bh % HH;
    const int s0 = c * CC;
    const int w = tid >> 6, lane = tid & 63, g = lane >> 4, ln = lane & 15;

    const int tA = w;                 // 16-row t-tile indices
    const int tB = 7 - w;
    const int nA = (w >> 1) + 1;      // causal 32-s-blocks for tile A: {1,1,2,2}
    const int nB = (9 - w) >> 1;      // for tile B: {4,4,3,3}  (sum = 5 for all waves)

    // async stage K, V^T, S0
    {
        const char* kbs = (const char*)kbg + (size_t)blk * 16384;
        const char* vts = (const char*)vtg + (size_t)blk * 16384;
        const char* s0s = (const char*)s0g + (size_t)blk * 8192;
        #pragma unroll
        for (int i = 0; i < 4; ++i) {
            gload16(kbs + w * 4096 + i * 1024 + lane * 16, KbL + w * 4096 + i * 1024);
            gload16(vts + w * 4096 + i * 1024 + lane * 16, VtL + w * 4096 + i * 1024);
        }
        #pragma unroll
        for (int i = 0; i < 2; ++i)
            gload16(s0s + w * 2048 + i * 1024 + lane * 16, S0L + w * 2048 + i * 1024);
        if (tid < DD) kzl[tid] = kzg[(size_t)blk * 64 + tid];
    }

    // q -> registers (phi + bf16) for both tiles
    bf16x8 aqA[2], aqB[2];
    #pragma unroll
    for (int kb2 = 0; kb2 < 2; ++kb2) {
        const float* qrowA = qk + ((size_t)((b * SS + s0 + tA * 16 + ln) * 2)) * (HH * DD) + h * DD;
        const float* qrowB = qk + ((size_t)((b * SS + s0 + tB * 16 + ln) * 2)) * (HH * DD) + h * DD;
        float4 a0 = *(const float4*)(qrowA + kb2 * 32 + g * 8);
        float4 a1 = *(const float4*)(qrowA + kb2 * 32 + g * 8 + 4);
        float4 b0 = *(const float4*)(qrowB + kb2 * 32 + g * 8);
        float4 b1 = *(const float4*)(qrowB + kb2 * 32 + g * 8 + 4);
        bf16x8 fa, fb;
        fa[0] = (short)f2bf(phi(a0.x)); fa[1] = (short)f2bf(phi(a0.y));
        fa[2] = (short)f2bf(phi(a0.z)); fa[3] = (short)f2bf(phi(a0.w));
        fa[4] = (short)f2bf(phi(a1.x)); fa[5] = (short)f2bf(phi(a1.y));
        fa[6] = (short)f2bf(phi(a1.z)); fa[7] = (short)f2bf(phi(a1.w));
        fb[0] = (short)f2bf(phi(b0.x)); fb[1] = (short)f2bf(phi(b0.y));
        fb[2] = (short)f2bf(phi(b0.z)); fb[3] = (short)f2bf(phi(b0.w));
        fb[4] = (short)f2bf(phi(b1.x)); fb[5] = (short)f2bf(phi(b1.y));
        fb[6] = (short)f2bf(phi(b1.z)); fb[7] = (short)f2bf(phi(b1.w));
        aqA[kb2] = fa;
        aqB[kb2] = fb;
    }
    __syncthreads();

    f32x4 OA[4], OB[4];
    #pragma unroll
    for (int n = 0; n < 4; ++n) {
        OA[n] = (f32x4){0.f, 0.f, 0.f, 0.f};
        OB[n] = (f32x4){0.f, 0.f, 0.f, 0.f};
    }

    // inter-chunk: O += Q * S0 (both tiles)
    #pragma unroll
    for (int n = 0; n < 4; ++n) {
        int e = n * 16 + ln;
        bf16x8 s0b0 = *(const bf16x8*)(S0L + e * 128 + ((g * 16) ^ ((e & 7) << 4)));
        bf16x8 s0b1 = *(const bf16x8*)(S0L + e * 128 + ((64 + g * 16) ^ ((e & 7) << 4)));
        OA[n] = __builtin_amdgcn_mfma_f32_16x16x32_bf16(aqA[0], s0b0, OA[n], 0, 0, 0);
        OA[n] = __builtin_amdgcn_mfma_f32_16x16x32_bf16(aqA[1], s0b1, OA[n], 0, 0, 0);
        OB[n] = __builtin_amdgcn_mfma_f32_16x16x32_bf16(aqB[0], s0b0, OB[n], 0, 0, 0);
        OB[n] = __builtin_amdgcn_mfma_f32_16x16x32_bf16(aqB[1], s0b1, OB[n], 0, 0, 0);
    }

    // nu base: q . kz
    float nuA = 0.f, nuB = 0.f;
    #pragma unroll
    for (int kb2 = 0; kb2 < 2; ++kb2)
        #pragma unroll
        for (int j = 0; j < 8; ++j) {
            float kzv = kzl[kb2 * 32 + g * 8 + j];
            nuA = fmaf(bf2f((unsigned short)aqA[kb2][j]), kzv, nuA);
            nuB = fmaf(bf2f((unsigned short)aqB[kb2][j]), kzv, nuB);
        }

    // causal s-block loop: every wave runs nB iterations; tile A active for sb<nA.
    for (int sb = 0; sb < nB; ++sb) {
        const bool doA = (sb < nA);
        const bool diagA = (sb == nA - 1);
        const bool diagB = (sb == nB - 1);

        // K frags for this s-block
        bf16x8 bk[2][2];
        #pragma unroll
        for (int ns = 0; ns < 2; ++ns) {
            int s = sb * 32 + ns * 16 + ln;
            const char* srow = KbL + s * 128;
            bk[ns][0] = *(const bf16x8*)(srow + ((g * 16) ^ ((s & 7) << 4)));
            bk[ns][1] = *(const bf16x8*)(srow + ((64 + g * 16) ^ ((s & 7) << 4)));
        }

        // QK^T
        f32x4 ScA[2], ScB[2];
        #pragma unroll
        for (int ns = 0; ns < 2; ++ns) {
            ScB[ns] = (f32x4){0.f, 0.f, 0.f, 0.f};
            ScB[ns] = __builtin_amdgcn_mfma_f32_16x16x32_bf16(aqB[0], bk[ns][0], ScB[ns], 0, 0, 0);
            ScB[ns] = __builtin_amdgcn_mfma_f32_16x16x32_bf16(aqB[1], bk[ns][1], ScB[ns], 0, 0, 0);
        }
        if (doA) {
            #pragma unroll
            for (int ns = 0; ns < 2; ++ns) {
                ScA[ns] = (f32x4){0.f, 0.f, 0.f, 0.f};
                ScA[ns] = __builtin_amdgcn_mfma_f32_16x16x32_bf16(aqA[0], bk[ns][0], ScA[ns], 0, 0, 0);
                ScA[ns] = __builtin_amdgcn_mfma_f32_16x16x32_bf16(aqA[1], bk[ns][1], ScA[ns], 0, 0, 0);
            }
        }

        // mask + bounce (f32 C-layout -> bf16 A-layout)
        #pragma unroll
        for (int ns = 0; ns < 2; ++ns)
            #pragma unroll
            for (int r = 0; r < 4; ++r) {
                int s_glob = sb * 32 + ns * 16 + ln;
                float vb = ScB[ns][r];
                if (diagB && s_glob > tB * 16 + g * 4 + r) vb = 0.f;
                Wl[w][1][g * 4 + r][ns * 16 + ln] = f2bf(vb);
                if (doA) {
                    float va = ScA[ns][r];
                    if (diagA && s_glob > tA * 16 + g * 4 + r) va = 0.f;
                    Wl[w][0][g * 4 + r][ns * 16 + ln] = f2bf(va);
                }
            }
        asm volatile("s_waitcnt lgkmcnt(0)" ::: "memory");
        __builtin_amdgcn_sched_barrier(0);

        // V frags
        bf16x8 bv[4];
        #pragma unroll
        for (int n = 0; n < 4; ++n) {
            int e = n * 16 + ln;
            bv[n] = *(const bf16x8*)(VtL + e * 256 + ((sb * 64 + g * 16) ^ ((e & 7) << 4)));
        }

        // PV + nu rowsums
        {
            bf16x8 pb = *(const bf16x8*)&Wl[w][1][ln][g * 8];
            float rs = 0.f;
            #pragma unroll
            for (int j = 0; j < 8; ++j) rs += bf2f((unsigned short)pb[j]);
            nuB += rs;
            #pragma unroll
            for (int n = 0; n < 4; ++n)
                OB[n] = __builtin_amdgcn_mfma_f32_16x16x32_bf16(pb, bv[n], OB[n], 0, 0, 0);
        }
        if (doA) {
            bf16x8 pa = *(const bf16x8*)&Wl[w][0][ln][g * 8];
            float rs = 0.f;
            #pragma unroll
            for (int j = 0; j < 8; ++j) rs += bf2f((unsigned short)pa[j]);
            nuA += rs;
            #pragma unroll
            for (int n = 0; n < 4; ++n)
                OA[n] = __builtin_amdgcn_mfma_f32_16x16x32_bf16(pa, bv[n], OA[n], 0, 0, 0);
        }
    }

    // nu reduce + normalize + store (both tiles)
    {
        float na = nuA, nb = nuB;
        na += __shfl_xor(na, 16); na += __shfl_xor(na, 32);
        nb += __shfl_xor(nb, 16); nb += __shfl_xor(nb, 32);
        if (g == 0) {
            nul[w][0][ln] = na;
            nul[w][1][ln] = nb;
        }
    }
    asm volatile("s_waitcnt lgkmcnt(0)" ::: "memory");
    __builtin_amdgcn_sched_barrier(0);

    #pragma unroll
    for (int tile = 0; tile < 2; ++tile) {
        const f32x4* O = tile ? OB : OA;
        int tbase = (tile ? tB : tA) * 16;
        float inv[4];
        #pragma unroll
        for (int r = 0; r < 4; ++r) inv[r] = 1.f / nul[w][tile][g * 4 + r];
        #pragma unroll
        for (int n = 0; n < 4; ++n)
            #pragma unroll
            for (int r = 0; r < 4; ++r) {
                int t = tbase + g * 4 + r;
                int e = n * 16 + ln;
                size_t oa = ((size_t)((b * SS + s0 + t) * HH + h)) * DD + e;
                out[oa] = O[n][r] * inv[r];
            }
    }
}

extern "C" void kernel_launch(void* const* d_in, const int* in_sizes, int n_in,
                              void* d_out, int out_size, void* d_ws, size_t ws_size,
                              hipStream_t stream) {
    const float* qk = (const float*)d_in[0];
    const float* v  = (const float*)d_in[1];
    float* outp = (float*)d_out;

    float* st = (float*)d_ws;
    unsigned short* kbg = (unsigned short*)((char*)d_ws + WS_KB);
    unsigned short* vtg = (unsigned short*)((char*)d_ws + WS_VT);
    unsigned short* s0g = (unsigned short*)((char*)d_ws + WS_S0);
    float* kzg = (float*)((char*)d_ws + WS_KZ);

    prep_state<<<NCHUNK, 256, 0, stream>>>(qk, v, st, kbg, vtg);
    chunk_scan<<<130, 256, 0, stream>>>(st, s0g, kzg);
    lin_attn_out<<<NCHUNK, 256, 0, stream>>>(qk, kbg, vtg, s0g, kzg, outp);
}